// Round 1
// baseline (2561.872 us; speedup 1.0000x reference)
//
#include <hip/hip_runtime.h>
#include <hip/hip_bf16.h>
#include <stdint.h>

// ---------------- problem constants ----------------
#define D_   1024
#define H_   16
#define HD_  64
#define F_   4096
#define NL_  4
#define B_   16
#define TT_  128
#define TS_  512
#define LP_  704                  // padded seq len: 11*64; B_*LP_ = 11264 = 88*128
#define M_   (B_*LP_)

typedef __attribute__((ext_vector_type(8)))  __bf16 bf16x8;
typedef __attribute__((ext_vector_type(4)))  float  floatx4;

typedef __attribute__((address_space(3))) void lds_void_t;
typedef const __attribute__((address_space(1))) void g_void_t;

__device__ __forceinline__ void gl2lds16(const __bf16* g, const __bf16* l) {
  // async global->LDS, 16B per lane; LDS dest = wave-uniform base + lane*16
  __builtin_amdgcn_global_load_lds((g_void_t*)g, (lds_void_t*)l, 16, 0, 0);
}

// ---------------- lens: tlen[b], Lb[b]=2+tlen+slen ----------------
__global__ void lens_kernel(const int* __restrict__ tmask, const int* __restrict__ smask,
                            int* __restrict__ lens) {
  __shared__ int red[256];
  int b = blockIdx.x, t = threadIdx.x;
  int tc = 0, sc = 0;
  if (t < TT_) tc = (tmask[b*TT_ + t] == 0) ? 1 : 0;
  for (int i = t; i < TS_; i += 256) sc += (smask[b*TS_ + i] == 0) ? 1 : 0;
  red[t] = tc + (sc << 16);
  __syncthreads();
  for (int s = 128; s > 0; s >>= 1) {
    if (t < s) red[t] += red[t + s];
    __syncthreads();
  }
  if (t == 0) {
    int tl = red[0] & 0xffff, sl = red[0] >> 16;
    if (tl < 0) tl = 0; if (tl > TT_) tl = TT_;
    if (sl < 0) sl = 0; if (sl > TS_) sl = TS_;
    int Lb = 2 + tl + sl;
    if (Lb > LP_) Lb = LP_;
    lens[2*b] = tl; lens[2*b+1] = Lb;
  }
}

// ---------------- fp32 [R,C] -> bf16 [C,R] transpose (batched over z) ----------------
__global__ void transpose_kernel(const float* __restrict__ in, __bf16* __restrict__ out,
                                 int R, int C) {
  __shared__ float tile[32][33];
  int x = threadIdx.x & 31, y0 = threadIdx.x >> 5;
  const float* inb = in + (size_t)blockIdx.z * R * C;
  __bf16* outb = out + (size_t)blockIdx.z * R * C;
  int r0 = blockIdx.y * 32, c0 = blockIdx.x * 32;
  #pragma unroll
  for (int i = 0; i < 4; i++) {
    int y = y0 + 8*i;
    tile[y][x] = inb[(size_t)(r0 + y)*C + c0 + x];
  }
  __syncthreads();
  #pragma unroll
  for (int i = 0; i < 4; i++) {
    int y = y0 + 8*i;
    outb[(size_t)(c0 + y)*R + r0 + x] = (__bf16)tile[x][y];
  }
}

// ---------------- build padded x (bf16): CLS | text | SEP | speech | 0 ----------------
__global__ void build_x_kernel(const float* __restrict__ text, const float* __restrict__ speech,
                               const float* __restrict__ cls, const float* __restrict__ sep,
                               const int* __restrict__ lens, __bf16* __restrict__ xbf) {
  int row = blockIdx.x;
  int b = row / LP_, l = row % LP_;
  int tl = lens[2*b], Lb = lens[2*b+1];
  const float* src = nullptr;          // nullptr => zero row
  if (l == 0)              src = cls;
  else if (l <= tl)        src = text   + ((size_t)(l-1)*B_ + b)*D_;       // [TT,B,D]
  else if (l == tl + 1)    src = sep;
  else if (l < Lb)         src = speech + ((size_t)(l-2-tl)*B_ + b)*D_;    // [TS,B,D]
  __bf16* dst = xbf + (size_t)row * D_;
  #pragma unroll
  for (int j = 0; j < 4; j++) {
    int i = threadIdx.x + j*256;
    float v = src ? src[i] : 0.f;
    dst[i] = (__bf16)v;
  }
}

// ---------------- GEMM: C[M,N] = A[M,K] @ BT[N,K]^T + bias ----------------
// MODE 0: fp32 out; 1: bf16 out; 2: bf16+relu; 3: bf16*scale
template<int MODE>
__global__ __launch_bounds__(256, 2)
void gemm_kernel(const __bf16* __restrict__ A, const __bf16* __restrict__ BT,
                 const float* __restrict__ bias, void* __restrict__ Cv,
                 int Nn, int Kk, float scale) {
  __shared__ __bf16 As[128*32];
  __shared__ __bf16 Bs[128*32];
  int tid = threadIdx.x;
  int w = tid >> 6, l = tid & 63;
  int wm = w >> 1, wn = w & 1;
  long tile_m = (long)blockIdx.y * 128;
  long tile_n = (long)blockIdx.x * 128;

  floatx4 acc[4][4] = {};

  const __bf16* ga = A  + (tile_m + w*32 + (l>>2)) * (long)Kk + (l&3)*8;
  const __bf16* gb = BT + (tile_n + w*32 + (l>>2)) * (long)Kk + (l&3)*8;
  const __bf16* lA = As + (w*32)*32;   // wave-uniform LDS base
  const __bf16* lB = Bs + (w*32)*32;

  int kcol = (l >> 4) * 8;
  const __bf16* afp = As + (wm*64 + (l&15))*32 + kcol;
  const __bf16* bfp = Bs + (wn*64 + (l&15))*32 + kcol;

  for (int k0 = 0; k0 < Kk; k0 += 32) {
    gl2lds16(ga,              lA);
    gl2lds16(ga + 16*(long)Kk, lA + 16*32);
    gl2lds16(gb,              lB);
    gl2lds16(gb + 16*(long)Kk, lB + 16*32);
    ga += 32; gb += 32;
    __syncthreads();
    bf16x8 af[4], bf[4];
    #pragma unroll
    for (int mi = 0; mi < 4; mi++) af[mi] = *(const bf16x8*)(afp + mi*16*32);
    #pragma unroll
    for (int ni = 0; ni < 4; ni++) bf[ni] = *(const bf16x8*)(bfp + ni*16*32);
    #pragma unroll
    for (int mi = 0; mi < 4; mi++)
      #pragma unroll
      for (int ni = 0; ni < 4; ni++)
        acc[mi][ni] = __builtin_amdgcn_mfma_f32_16x16x32_bf16(af[mi], bf[ni], acc[mi][ni], 0, 0, 0);
    __syncthreads();
  }

  int rbase = wm*64 + (l>>4)*4;
  int cbase = wn*64 + (l&15);
  #pragma unroll
  for (int mi = 0; mi < 4; mi++) {
    #pragma unroll
    for (int ni = 0; ni < 4; ni++) {
      long col = tile_n + cbase + ni*16;
      float bv = bias[col];
      #pragma unroll
      for (int r = 0; r < 4; r++) {
        long row = tile_m + rbase + mi*16 + r;
        float v = acc[mi][ni][r] + bv;
        if (MODE == 3) v *= scale;
        if (MODE == 2) v = v > 0.f ? v : 0.f;
        if (MODE == 0) ((float*)Cv)[row*Nn + col] = v;
        else           ((__bf16*)Cv)[row*Nn + col] = (__bf16)v;
      }
    }
  }
}

// ---------------- flash attention: q,k,v [B,LP,H,HD] bf16 -> o bf16 ----------------
__global__ __launch_bounds__(256, 2)
void attn_kernel(const __bf16* __restrict__ qb, const __bf16* __restrict__ kb,
                 const __bf16* __restrict__ vb, __bf16* __restrict__ ob,
                 const int* __restrict__ lens) {
  __shared__ __bf16 Ks[64*64];        // [key][hd]
  __shared__ __bf16 Vt[64*72];        // [hd][key], padded stride 72
  __shared__ __bf16 Ps[4][16*72];     // per-wave P tile, padded stride 72
  int tid = threadIdx.x, w = tid >> 6, l = tid & 63;
  int h = blockIdx.y, b = blockIdx.z;
  int q0 = blockIdx.x*64 + w*16;
  int Lb = lens[2*b+1];
  const size_t bh = ((size_t)b*LP_)*D_ + (size_t)h*HD_;

  bf16x8 qf[2];
  {
    const __bf16* qp = qb + bh + (size_t)(q0 + (l&15))*D_ + (l>>4)*8;
    qf[0] = *(const bf16x8*)(qp);
    qf[1] = *(const bf16x8*)(qp + 32);
  }
  floatx4 oacc[4] = {};
  float mrow[4], lrow[4];
  #pragma unroll
  for (int r = 0; r < 4; r++) { mrow[r] = -3e38f; lrow[r] = 0.f; }

  for (int kt = 0; kt < LP_/64; kt++) {
    int kbase = kt*64;
    { // stage K tile (async 16B)
      const __bf16* gk = kb + bh + (size_t)(kbase + w*16 + (l>>3))*D_ + (l&7)*8;
      const __bf16* lk = Ks + (w*16)*64;
      gl2lds16(gk,        lk);
      gl2lds16(gk + 8*D_, lk + 8*64);
    }
    // stage V transposed (VGPR path, scattered b16 writes)
    #pragma unroll
    for (int it = 0; it < 2; it++) {
      int key = (tid>>3) + it*32;
      int hd0 = (tid&7)*8;
      bf16x8 vv = *(const bf16x8*)(vb + bh + (size_t)(kbase + key)*D_ + hd0);
      #pragma unroll
      for (int j = 0; j < 8; j++) Vt[(hd0 + j)*72 + key] = vv[j];
    }
    __syncthreads();

    // S = Q K^T  (rows q0..q0+15, cols kbase..kbase+63)
    floatx4 s[4] = {};
    #pragma unroll
    for (int ks = 0; ks < 2; ks++) {
      #pragma unroll
      for (int ni = 0; ni < 4; ni++) {
        bf16x8 kf = *(const bf16x8*)(Ks + (ni*16 + (l&15))*64 + ks*32 + (l>>4)*8);
        s[ni] = __builtin_amdgcn_mfma_f32_16x16x32_bf16(qf[ks], kf, s[ni], 0, 0, 0);
      }
    }
    // mask + online softmax (state per row = quad*4+r)
    float mx[4];
    #pragma unroll
    for (int r = 0; r < 4; r++) mx[r] = -3e38f;
    #pragma unroll
    for (int ni = 0; ni < 4; ni++) {
      int key = kbase + ni*16 + (l&15);
      bool valid = key < Lb;
      #pragma unroll
      for (int r = 0; r < 4; r++) {
        float sv = valid ? s[ni][r] : -1e9f;
        s[ni][r] = sv;
        mx[r] = fmaxf(mx[r], sv);
      }
    }
    #pragma unroll
    for (int off = 1; off < 16; off <<= 1)
      #pragma unroll
      for (int r = 0; r < 4; r++) mx[r] = fmaxf(mx[r], __shfl_xor(mx[r], off, 16));

    float alpha[4], rsum[4];
    #pragma unroll
    for (int r = 0; r < 4; r++) {
      float mn = fmaxf(mrow[r], mx[r]);
      alpha[r] = __expf(mrow[r] - mn);
      mrow[r] = mn;
      rsum[r] = 0.f;
    }
    #pragma unroll
    for (int ni = 0; ni < 4; ni++) {
      #pragma unroll
      for (int r = 0; r < 4; r++) {
        float p = __expf(s[ni][r] - mrow[r]);
        rsum[r] += p;
        Ps[w][((l>>4)*4 + r)*72 + ni*16 + (l&15)] = (__bf16)p;
      }
    }
    #pragma unroll
    for (int off = 1; off < 16; off <<= 1)
      #pragma unroll
      for (int r = 0; r < 4; r++) rsum[r] += __shfl_xor(rsum[r], off, 16);
    #pragma unroll
    for (int r = 0; r < 4; r++) lrow[r] = lrow[r]*alpha[r] + rsum[r];
    #pragma unroll
    for (int ni = 0; ni < 4; ni++)
      #pragma unroll
      for (int r = 0; r < 4; r++) oacc[ni][r] *= alpha[r];

    // O += P V   (P via per-wave LDS round-trip, A-layout; V from Vt)
    #pragma unroll
    for (int ks = 0; ks < 2; ks++) {
      bf16x8 pf = *(const bf16x8*)(&Ps[w][(l&15)*72 + ks*32 + (l>>4)*8]);
      #pragma unroll
      for (int ni = 0; ni < 4; ni++) {
        bf16x8 vf = *(const bf16x8*)(&Vt[(ni*16 + (l&15))*72 + ks*32 + (l>>4)*8]);
        oacc[ni] = __builtin_amdgcn_mfma_f32_16x16x32_bf16(pf, vf, oacc[ni], 0, 0, 0);
      }
    }
    __syncthreads();
  }

  #pragma unroll
  for (int ni = 0; ni < 4; ni++) {
    #pragma unroll
    for (int r = 0; r < 4; r++) {
      int qrow = q0 + (l>>4)*4 + r;
      float ov = oacc[ni][r] / lrow[r];
      ob[bh + (size_t)qrow*D_ + ni*16 + (l&15)] = (__bf16)ov;
    }
  }
}

// ---------------- post-norm LN: x = LN(x + t)*s + b (in-place on bf16 x) ----------------
__global__ void ln_kernel(__bf16* __restrict__ x, const float* __restrict__ t,
                          const float* __restrict__ sc, const float* __restrict__ bi) {
  __shared__ float red[2][4];
  int row = blockIdx.x, tid = threadIdx.x;
  const float* tr = t + (size_t)row * D_;
  __bf16* xr = x + (size_t)row * D_;
  float v[4], s1 = 0.f, s2 = 0.f;
  #pragma unroll
  for (int j = 0; j < 4; j++) {
    int i = tid + j*256;
    float val = (float)xr[i] + tr[i];
    v[j] = val; s1 += val; s2 += val*val;
  }
  #pragma unroll
  for (int off = 1; off < 64; off <<= 1) {
    s1 += __shfl_xor(s1, off, 64);
    s2 += __shfl_xor(s2, off, 64);
  }
  int w = tid >> 6, l = tid & 63;
  if (l == 0) { red[0][w] = s1; red[1][w] = s2; }
  __syncthreads();
  s1 = red[0][0] + red[0][1] + red[0][2] + red[0][3];
  s2 = red[1][0] + red[1][1] + red[1][2] + red[1][3];
  float mean = s1 * (1.f/D_);
  float var  = s2 * (1.f/D_) - mean*mean;
  float rstd = rsqrtf(var + 1e-5f);
  #pragma unroll
  for (int j = 0; j < 4; j++) {
    int i = tid + j*256;
    xr[i] = (__bf16)((v[j] - mean)*rstd*sc[i] + bi[i]);
  }
}

// ---------------- final: out[b] = dot(x[b,0,:], out_w) ----------------
__global__ void out_kernel(const __bf16* __restrict__ x, const float* __restrict__ wv,
                           float* __restrict__ out) {
  __shared__ float red[4];
  int b = blockIdx.x, tid = threadIdx.x;
  const __bf16* xr = x + (size_t)b * LP_ * D_;
  float s = 0.f;
  #pragma unroll
  for (int j = 0; j < 4; j++) {
    int i = tid + j*256;
    s += (float)xr[i] * wv[i];
  }
  #pragma unroll
  for (int off = 1; off < 64; off <<= 1) s += __shfl_xor(s, off, 64);
  int w = tid >> 6, l = tid & 63;
  if (l == 0) red[w] = s;
  __syncthreads();
  if (tid == 0) out[b] = red[0] + red[1] + red[2] + red[3];
}

// ---------------- launch ----------------
extern "C" void kernel_launch(void* const* d_in, const int* in_sizes, int n_in,
                              void* d_out, int out_size, void* d_ws, size_t ws_size,
                              hipStream_t stream) {
  (void)in_sizes; (void)n_in; (void)out_size; (void)ws_size;
  const float* text   = (const float*)d_in[0];
  const float* speech = (const float*)d_in[1];
  const int*   tmask  = (const int*)d_in[2];
  const int*   smask  = (const int*)d_in[3];
  const float* cls    = (const float*)d_in[4];
  const float* sep    = (const float*)d_in[5];
  const float* Wq     = (const float*)d_in[6];
  const float* bq     = (const float*)d_in[7];
  const float* Wk     = (const float*)d_in[8];
  const float* bk     = (const float*)d_in[9];
  const float* Wv     = (const float*)d_in[10];
  const float* bv     = (const float*)d_in[11];
  const float* Wo     = (const float*)d_in[12];
  const float* bo     = (const float*)d_in[13];
  const float* ln1s   = (const float*)d_in[14];
  const float* ln1b   = (const float*)d_in[15];
  const float* fc1w   = (const float*)d_in[16];
  const float* fc1b   = (const float*)d_in[17];
  const float* fc2w   = (const float*)d_in[18];
  const float* fc2b   = (const float*)d_in[19];
  const float* ln2s   = (const float*)d_in[20];
  const float* ln2b   = (const float*)d_in[21];
  const float* outw   = (const float*)d_in[22];

  const size_t MD = (size_t)M_ * D_;            // 11,534,336 elems
  char* ws = (char*)d_ws;
  int*    lens = (int*)ws;
  __bf16* xbf  = (__bf16*)(ws + 256);
  __bf16* act  = (__bf16*)(ws + 256 + MD*2);            // q|k|v|o, reused as h
  float*  tmp  = (float*) (ws + 256 + MD*2 + 4*MD*2);
  __bf16* wt   = (__bf16*)(ws + 256 + MD*2 + 4*MD*2 + MD*4);

  __bf16* qb = act;
  __bf16* kb = act + MD;
  __bf16* vb = act + 2*MD;
  __bf16* obuf = act + 3*MD;
  __bf16* hb = act;                              // [M, F] after attention phase

  const size_t DD = (size_t)D_*D_;               // 1,048,576
  const size_t DF = (size_t)D_*F_;               // 4,194,304
  __bf16* wqT  = wt;
  __bf16* wkT  = wt + 4*DD;
  __bf16* wvT  = wt + 8*DD;
  __bf16* woT  = wt + 12*DD;
  __bf16* fc1T = wt + 16*DD;
  __bf16* fc2T = wt + 16*DD + 4*DF;

  lens_kernel<<<B_, 256, 0, stream>>>(tmask, smask, lens);

  transpose_kernel<<<dim3(D_/32, D_/32, NL_), 256, 0, stream>>>(Wq, wqT, D_, D_);
  transpose_kernel<<<dim3(D_/32, D_/32, NL_), 256, 0, stream>>>(Wk, wkT, D_, D_);
  transpose_kernel<<<dim3(D_/32, D_/32, NL_), 256, 0, stream>>>(Wv, wvT, D_, D_);
  transpose_kernel<<<dim3(D_/32, D_/32, NL_), 256, 0, stream>>>(Wo, woT, D_, D_);
  transpose_kernel<<<dim3(F_/32, D_/32, NL_), 256, 0, stream>>>(fc1w, fc1T, D_, F_);
  transpose_kernel<<<dim3(D_/32, F_/32, NL_), 256, 0, stream>>>(fc2w, fc2T, F_, D_);

  build_x_kernel<<<M_, 256, 0, stream>>>(text, speech, cls, sep, lens, xbf);

  for (int lyr = 0; lyr < NL_; lyr++) {
    gemm_kernel<3><<<dim3(D_/128, M_/128), 256, 0, stream>>>(xbf, wqT + lyr*DD, bq + lyr*D_, qb, D_, D_, 0.125f);
    gemm_kernel<1><<<dim3(D_/128, M_/128), 256, 0, stream>>>(xbf, wkT + lyr*DD, bk + lyr*D_, kb, D_, D_, 1.f);
    gemm_kernel<1><<<dim3(D_/128, M_/128), 256, 0, stream>>>(xbf, wvT + lyr*DD, bv + lyr*D_, vb, D_, D_, 1.f);
    attn_kernel<<<dim3(LP_/64, H_, B_), 256, 0, stream>>>(qb, kb, vb, obuf, lens);
    gemm_kernel<0><<<dim3(D_/128, M_/128), 256, 0, stream>>>(obuf, woT + lyr*DD, bo + lyr*D_, tmp, D_, D_, 1.f);
    ln_kernel<<<M_, 256, 0, stream>>>(xbf, tmp, ln1s + lyr*D_, ln1b + lyr*D_);
    gemm_kernel<2><<<dim3(F_/128, M_/128), 256, 0, stream>>>(xbf, fc1T + lyr*DF, fc1b + lyr*F_, hb, F_, D_, 1.f);
    gemm_kernel<0><<<dim3(D_/128, M_/128), 256, 0, stream>>>(hb, fc2T + lyr*DF, fc2b + lyr*D_, tmp, D_, F_, 1.f);
    ln_kernel<<<M_, 256, 0, stream>>>(xbf, tmp, ln2s + lyr*D_, ln2b + lyr*D_);
  }

  out_kernel<<<B_, 256, 0, stream>>>(xbf, outw, (float*)d_out);
}

// Round 2
// 2243.014 us; speedup vs baseline: 1.1422x; 1.1422x over previous
//
#include <hip/hip_runtime.h>
#include <hip/hip_bf16.h>
#include <stdint.h>

// ---------------- problem constants ----------------
#define D_   1024
#define H_   16
#define HD_  64
#define F_   4096
#define NL_  4
#define B_   16
#define TT_  128
#define TS_  512
#define LP_  704                  // padded seq len: 11*64; B_*LP_ = 11264 = 88*128
#define M_   (B_*LP_)

typedef __attribute__((ext_vector_type(8)))  __bf16 bf16x8;
typedef __attribute__((ext_vector_type(4)))  float  floatx4;

typedef __attribute__((address_space(3))) void lds_void_t;
typedef const __attribute__((address_space(1))) void g_void_t;

__device__ __forceinline__ void gl2lds16(const __bf16* g, const __bf16* l) {
  // async global->LDS, 16B per lane; LDS dest = wave-uniform base + lane*16
  __builtin_amdgcn_global_load_lds((g_void_t*)g, (lds_void_t*)l, 16, 0, 0);
}

// ---------------- lens: tlen[b], Lb[b]=2+tlen+slen ----------------
__global__ void lens_kernel(const int* __restrict__ tmask, const int* __restrict__ smask,
                            int* __restrict__ lens) {
  __shared__ int red[256];
  int b = blockIdx.x, t = threadIdx.x;
  int tc = 0, sc = 0;
  if (t < TT_) tc = (tmask[b*TT_ + t] == 0) ? 1 : 0;
  for (int i = t; i < TS_; i += 256) sc += (smask[b*TS_ + i] == 0) ? 1 : 0;
  red[t] = tc + (sc << 16);
  __syncthreads();
  for (int s = 128; s > 0; s >>= 1) {
    if (t < s) red[t] += red[t + s];
    __syncthreads();
  }
  if (t == 0) {
    int tl = red[0] & 0xffff, sl = red[0] >> 16;
    if (tl < 0) tl = 0; if (tl > TT_) tl = TT_;
    if (sl < 0) sl = 0; if (sl > TS_) sl = TS_;
    int Lb = 2 + tl + sl;
    if (Lb > LP_) Lb = LP_;
    lens[2*b] = tl; lens[2*b+1] = Lb;
  }
}

// ---------------- fp32 [R,C] -> bf16 [C,R] transpose (batched over z) ----------------
__global__ void transpose_kernel(const float* __restrict__ in, __bf16* __restrict__ out,
                                 int R, int C) {
  __shared__ float tile[32][33];
  int x = threadIdx.x & 31, y0 = threadIdx.x >> 5;
  const float* inb = in + (size_t)blockIdx.z * R * C;
  __bf16* outb = out + (size_t)blockIdx.z * R * C;
  int r0 = blockIdx.y * 32, c0 = blockIdx.x * 32;
  #pragma unroll
  for (int i = 0; i < 4; i++) {
    int y = y0 + 8*i;
    tile[y][x] = inb[(size_t)(r0 + y)*C + c0 + x];
  }
  __syncthreads();
  #pragma unroll
  for (int i = 0; i < 4; i++) {
    int y = y0 + 8*i;
    outb[(size_t)(c0 + y)*R + r0 + x] = (__bf16)tile[x][y];
  }
}

// ---------------- build padded x (bf16): CLS | text | SEP | speech | 0 ----------------
__global__ void build_x_kernel(const float* __restrict__ text, const float* __restrict__ speech,
                               const float* __restrict__ cls, const float* __restrict__ sep,
                               const int* __restrict__ lens, __bf16* __restrict__ xbf) {
  int row = blockIdx.x;
  int b = row / LP_, l = row % LP_;
  int tl = lens[2*b], Lb = lens[2*b+1];
  const float* src = nullptr;          // nullptr => zero row
  if (l == 0)              src = cls;
  else if (l <= tl)        src = text   + ((size_t)(l-1)*B_ + b)*D_;       // [TT,B,D]
  else if (l == tl + 1)    src = sep;
  else if (l < Lb)         src = speech + ((size_t)(l-2-tl)*B_ + b)*D_;    // [TS,B,D]
  __bf16* dst = xbf + (size_t)row * D_;
  #pragma unroll
  for (int j = 0; j < 4; j++) {
    int i = threadIdx.x + j*256;
    float v = src ? src[i] : 0.f;
    dst[i] = (__bf16)v;
  }
}

// ---------------- GEMM: C[M,N] = A[M,K] @ BT[N,K]^T + bias ----------------
// MODE 0: fp32 out; 1: bf16 out; 2: bf16+relu; 3: bf16*scale; 4: bf16 transposed V store
template<int MODE>
__global__ __launch_bounds__(256, 2)
void gemm_kernel(const __bf16* __restrict__ A, const __bf16* __restrict__ BT,
                 const float* __restrict__ bias, void* __restrict__ Cv,
                 int Nn, int Kk, float scale) {
  __shared__ __bf16 As[128*32];
  __shared__ __bf16 Bs[128*32];
  int tid = threadIdx.x;
  int w = tid >> 6, l = tid & 63;
  int wm = w >> 1, wn = w & 1;
  long tile_m = (long)blockIdx.y * 128;
  long tile_n = (long)blockIdx.x * 128;

  floatx4 acc[4][4] = {};

  const __bf16* ga = A  + (tile_m + w*32 + (l>>2)) * (long)Kk + (l&3)*8;
  const __bf16* gb = BT + (tile_n + w*32 + (l>>2)) * (long)Kk + (l&3)*8;
  const __bf16* lA = As + (w*32)*32;   // wave-uniform LDS base
  const __bf16* lB = Bs + (w*32)*32;

  int kcol = (l >> 4) * 8;
  const __bf16* afp = As + (wm*64 + (l&15))*32 + kcol;
  const __bf16* bfp = Bs + (wn*64 + (l&15))*32 + kcol;

  for (int k0 = 0; k0 < Kk; k0 += 32) {
    gl2lds16(ga,              lA);
    gl2lds16(ga + 16*(long)Kk, lA + 16*32);
    gl2lds16(gb,              lB);
    gl2lds16(gb + 16*(long)Kk, lB + 16*32);
    ga += 32; gb += 32;
    __syncthreads();
    bf16x8 af[4], bf[4];
    #pragma unroll
    for (int mi = 0; mi < 4; mi++) af[mi] = *(const bf16x8*)(afp + mi*16*32);
    #pragma unroll
    for (int ni = 0; ni < 4; ni++) bf[ni] = *(const bf16x8*)(bfp + ni*16*32);
    #pragma unroll
    for (int mi = 0; mi < 4; mi++)
      #pragma unroll
      for (int ni = 0; ni < 4; ni++)
        acc[mi][ni] = __builtin_amdgcn_mfma_f32_16x16x32_bf16(af[mi], bf[ni], acc[mi][ni], 0, 0, 0);
    __syncthreads();
  }

  int rbase = wm*64 + (l>>4)*4;
  int cbase = wn*64 + (l&15);
  #pragma unroll
  for (int mi = 0; mi < 4; mi++) {
    #pragma unroll
    for (int ni = 0; ni < 4; ni++) {
      long col = tile_n + cbase + ni*16;
      float bv = bias[col];
      #pragma unroll
      for (int r = 0; r < 4; r++) {
        long row = tile_m + rbase + mi*16 + r;
        float v = acc[mi][ni][r] + bv;
        if (MODE == 3) v *= scale;
        if (MODE == 2) v = v > 0.f ? v : 0.f;
        if (MODE == 0)      ((float*)Cv)[row*Nn + col] = v;
        else if (MODE == 4) {
          int b = (int)(row / LP_);
          int ll = (int)(row - (long)b * LP_);
          // Vt[b][h][hd][l], col = h*64+hd
          ((__bf16*)Cv)[(((long)b*H_ + (col>>6))*HD_ + (col&63))*LP_ + ll] = (__bf16)v;
        }
        else                ((__bf16*)Cv)[row*Nn + col] = (__bf16)v;
      }
    }
  }
}

// ---------------- flash attention ----------------
// q,k [B,LP,H,HD] bf16; vt [B,H,HD,LP] bf16 -> o [B,LP,H,HD] bf16
// Block: 128 q-rows (4 waves x 32), grid (B*H, LP/128 rounded up)
__global__ __launch_bounds__(256, 2)
void attn_kernel(const __bf16* __restrict__ qb, const __bf16* __restrict__ kb,
                 const __bf16* __restrict__ vt, __bf16* __restrict__ ob,
                 const int* __restrict__ lens) {
  __shared__ __bf16 Ks[64*64];        // [key][hd-block ^ (key&7)]
  __shared__ __bf16 Vs[64*64];        // [hd][key-block ^ (hd&7)]
  __shared__ __bf16 Ps[4][32*72];     // per-wave P (2 m-frags), stride 72
  int tid = threadIdx.x, w = tid >> 6, l = tid & 63;
  int col = blockIdx.x;               // b*H + h
  int b = col >> 4;
  int Lb = lens[2*b+1];
  int q0w = blockIdx.y*128 + w*32;    // wave's first q row
  const size_t bh  = ((size_t)b*LP_)*D_ + (size_t)(col & 15)*HD_;
  const size_t vtb = (size_t)col * HD_ * LP_;

  // Q fragments: A[m=q-row][k=hd], 2 m-frags x 2 k-halves
  bf16x8 qf[2][2];
  #pragma unroll
  for (int mi = 0; mi < 2; mi++) {
    int qr = q0w + mi*16 + (l&15);
    if (qr > LP_-1) qr = LP_-1;
    const __bf16* qp = qb + bh + (size_t)qr*D_ + (l>>4)*8;
    qf[mi][0] = *(const bf16x8*)(qp);
    qf[mi][1] = *(const bf16x8*)(qp + 32);
  }
  bf16x8 ones;
  #pragma unroll
  for (int j = 0; j < 8; j++) ones[j] = (__bf16)1.0f;

  floatx4 oacc[2][4] = {};
  floatx4 lacc[2] = {};

  for (int kt = 0; kt < LP_/64; kt++) {
    int kbase = kt*64;
    { // stage K tile: rows=key, 8 hd-blocks XOR-swizzled by key&7
      int krow = w*16 + (l>>3);
      int cb = (l&7) ^ (krow & 7);
      const __bf16* gk = kb + bh + (size_t)(kbase + krow)*D_ + cb*8;
      const __bf16* lk = Ks + (w*16)*64;
      gl2lds16(gk,               lk);
      gl2lds16(gk + 8*(size_t)D_, lk + 8*64);
    }
    { // stage V^T tile: rows=hd, 8 key-blocks XOR-swizzled by hd&7
      int vrow = w*8 + (l>>3);
      int sb = (l&7) ^ (l>>3);
      const __bf16* gv = vt + vtb + (size_t)vrow*LP_ + kbase + sb*8;
      const __bf16* lv = Vs + (w*8)*64;
      gl2lds16(gv,                 lv);
      gl2lds16(gv + 32*(size_t)LP_, lv + 32*64);
    }
    __syncthreads();

    // S = Q K^T for both m-frags (kf loaded once, used twice)
    floatx4 s4[2][4] = {};
    #pragma unroll
    for (int ks = 0; ks < 2; ks++) {
      #pragma unroll
      for (int ni = 0; ni < 4; ni++) {
        int n = ni*16 + (l&15);
        int blk = (ks*4 + (l>>4)) ^ (n & 7);
        bf16x8 kf = *(const bf16x8*)(Ks + n*64 + blk*8);
        s4[0][ni] = __builtin_amdgcn_mfma_f32_16x16x32_bf16(qf[0][ks], kf, s4[0][ni], 0, 0, 0);
        s4[1][ni] = __builtin_amdgcn_mfma_f32_16x16x32_bf16(qf[1][ks], kf, s4[1][ni], 0, 0, 0);
      }
    }
    // mask + exp (no max subtraction: |s| bounded, clamp at 30 for safety)
    #pragma unroll
    for (int mi = 0; mi < 2; mi++) {
      #pragma unroll
      for (int ni = 0; ni < 4; ni++) {
        int key = kbase + ni*16 + (l&15);
        bool valid = key < Lb;
        #pragma unroll
        for (int r = 0; r < 4; r++) {
          float sv = valid ? fminf(s4[mi][ni][r], 30.f) : -1e9f;
          float p = __expf(sv);
          Ps[w][(mi*16 + (l>>4)*4 + r)*72 + ni*16 + (l&15)] = (__bf16)p;
        }
      }
    }
    // O += P V; row-sum via ones-vector MFMA (vf loaded once, used twice)
    #pragma unroll
    for (int ks = 0; ks < 2; ks++) {
      bf16x8 pf0 = *(const bf16x8*)(&Ps[w][(l&15)*72 + ks*32 + (l>>4)*8]);
      bf16x8 pf1 = *(const bf16x8*)(&Ps[w][(16 + (l&15))*72 + ks*32 + (l>>4)*8]);
      lacc[0] = __builtin_amdgcn_mfma_f32_16x16x32_bf16(pf0, ones, lacc[0], 0, 0, 0);
      lacc[1] = __builtin_amdgcn_mfma_f32_16x16x32_bf16(pf1, ones, lacc[1], 0, 0, 0);
      #pragma unroll
      for (int ni = 0; ni < 4; ni++) {
        int n = ni*16 + (l&15);
        int blk = (ks*4 + (l>>4)) ^ (n & 7);
        bf16x8 vf = *(const bf16x8*)(Vs + n*64 + blk*8);
        oacc[0][ni] = __builtin_amdgcn_mfma_f32_16x16x32_bf16(pf0, vf, oacc[0][ni], 0, 0, 0);
        oacc[1][ni] = __builtin_amdgcn_mfma_f32_16x16x32_bf16(pf1, vf, oacc[1][ni], 0, 0, 0);
      }
    }
    __syncthreads();
  }

  #pragma unroll
  for (int mi = 0; mi < 2; mi++) {
    #pragma unroll
    for (int ni = 0; ni < 4; ni++) {
      #pragma unroll
      for (int r = 0; r < 4; r++) {
        int qrow = q0w + mi*16 + (l>>4)*4 + r;
        if (qrow < LP_) {
          float ov = oacc[mi][ni][r] / lacc[mi][r];
          ob[bh + (size_t)qrow*D_ + ni*16 + (l&15)] = (__bf16)ov;
        }
      }
    }
  }
}

// ---------------- post-norm LN: x = LN(x + t)*s + b (in-place on bf16 x) ----------------
__global__ void ln_kernel(__bf16* __restrict__ x, const float* __restrict__ t,
                          const float* __restrict__ sc, const float* __restrict__ bi) {
  __shared__ float red[2][4];
  int row = blockIdx.x, tid = threadIdx.x;
  const float* tr = t + (size_t)row * D_;
  __bf16* xr = x + (size_t)row * D_;
  float v[4], s1 = 0.f, s2 = 0.f;
  #pragma unroll
  for (int j = 0; j < 4; j++) {
    int i = tid + j*256;
    float val = (float)xr[i] + tr[i];
    v[j] = val; s1 += val; s2 += val*val;
  }
  #pragma unroll
  for (int off = 1; off < 64; off <<= 1) {
    s1 += __shfl_xor(s1, off, 64);
    s2 += __shfl_xor(s2, off, 64);
  }
  int w = tid >> 6, l = tid & 63;
  if (l == 0) { red[0][w] = s1; red[1][w] = s2; }
  __syncthreads();
  s1 = red[0][0] + red[0][1] + red[0][2] + red[0][3];
  s2 = red[1][0] + red[1][1] + red[1][2] + red[1][3];
  float mean = s1 * (1.f/D_);
  float var  = s2 * (1.f/D_) - mean*mean;
  float rstd = rsqrtf(var + 1e-5f);
  #pragma unroll
  for (int j = 0; j < 4; j++) {
    int i = tid + j*256;
    xr[i] = (__bf16)((v[j] - mean)*rstd*sc[i] + bi[i]);
  }
}

// ---------------- final: out[b] = dot(x[b,0,:], out_w) ----------------
__global__ void out_kernel(const __bf16* __restrict__ x, const float* __restrict__ wv,
                           float* __restrict__ out) {
  __shared__ float red[4];
  int b = blockIdx.x, tid = threadIdx.x;
  const __bf16* xr = x + (size_t)b * LP_ * D_;
  float s = 0.f;
  #pragma unroll
  for (int j = 0; j < 4; j++) {
    int i = tid + j*256;
    s += (float)xr[i] * wv[i];
  }
  #pragma unroll
  for (int off = 1; off < 64; off <<= 1) s += __shfl_xor(s, off, 64);
  int w = tid >> 6, l = tid & 63;
  if (l == 0) red[w] = s;
  __syncthreads();
  if (tid == 0) out[b] = red[0] + red[1] + red[2] + red[3];
}

// ---------------- launch ----------------
extern "C" void kernel_launch(void* const* d_in, const int* in_sizes, int n_in,
                              void* d_out, int out_size, void* d_ws, size_t ws_size,
                              hipStream_t stream) {
  (void)in_sizes; (void)n_in; (void)out_size; (void)ws_size;
  const float* text   = (const float*)d_in[0];
  const float* speech = (const float*)d_in[1];
  const int*   tmask  = (const int*)d_in[2];
  const int*   smask  = (const int*)d_in[3];
  const float* cls    = (const float*)d_in[4];
  const float* sep    = (const float*)d_in[5];
  const float* Wq     = (const float*)d_in[6];
  const float* bq     = (const float*)d_in[7];
  const float* Wk     = (const float*)d_in[8];
  const float* bk     = (const float*)d_in[9];
  const float* Wv     = (const float*)d_in[10];
  const float* bv     = (const float*)d_in[11];
  const float* Wo     = (const float*)d_in[12];
  const float* bo     = (const float*)d_in[13];
  const float* ln1s   = (const float*)d_in[14];
  const float* ln1b   = (const float*)d_in[15];
  const float* fc1w   = (const float*)d_in[16];
  const float* fc1b   = (const float*)d_in[17];
  const float* fc2w   = (const float*)d_in[18];
  const float* fc2b   = (const float*)d_in[19];
  const float* ln2s   = (const float*)d_in[20];
  const float* ln2b   = (const float*)d_in[21];
  const float* outw   = (const float*)d_in[22];

  const size_t MD = (size_t)M_ * D_;            // 11,534,336 elems
  char* ws = (char*)d_ws;
  int*    lens = (int*)ws;
  __bf16* xbf  = (__bf16*)(ws + 256);
  __bf16* act  = (__bf16*)(ws + 256 + MD*2);            // q|k|vt|o, reused as h
  float*  tmp  = (float*) (ws + 256 + MD*2 + 4*MD*2);
  __bf16* wt   = (__bf16*)(ws + 256 + MD*2 + 4*MD*2 + MD*4);

  __bf16* qb  = act;
  __bf16* kb  = act + MD;
  __bf16* vtG = act + 2*MD;                      // [B,H,HD,LP]
  __bf16* obuf = act + 3*MD;
  __bf16* hb = act;                              // [M, F] after attention phase

  const size_t DD = (size_t)D_*D_;               // 1,048,576
  const size_t DF = (size_t)D_*F_;               // 4,194,304
  __bf16* wqT  = wt;
  __bf16* wkT  = wt + 4*DD;
  __bf16* wvT  = wt + 8*DD;
  __bf16* woT  = wt + 12*DD;
  __bf16* fc1T = wt + 16*DD;
  __bf16* fc2T = wt + 16*DD + 4*DF;

  lens_kernel<<<B_, 256, 0, stream>>>(tmask, smask, lens);

  transpose_kernel<<<dim3(D_/32, D_/32, NL_), 256, 0, stream>>>(Wq, wqT, D_, D_);
  transpose_kernel<<<dim3(D_/32, D_/32, NL_), 256, 0, stream>>>(Wk, wkT, D_, D_);
  transpose_kernel<<<dim3(D_/32, D_/32, NL_), 256, 0, stream>>>(Wv, wvT, D_, D_);
  transpose_kernel<<<dim3(D_/32, D_/32, NL_), 256, 0, stream>>>(Wo, woT, D_, D_);
  transpose_kernel<<<dim3(F_/32, D_/32, NL_), 256, 0, stream>>>(fc1w, fc1T, D_, F_);
  transpose_kernel<<<dim3(D_/32, F_/32, NL_), 256, 0, stream>>>(fc2w, fc2T, F_, D_);

  build_x_kernel<<<M_, 256, 0, stream>>>(text, speech, cls, sep, lens, xbf);

  for (int lyr = 0; lyr < NL_; lyr++) {
    gemm_kernel<3><<<dim3(D_/128, M_/128), 256, 0, stream>>>(xbf, wqT + lyr*DD, bq + lyr*D_, qb, D_, D_, 0.125f);
    gemm_kernel<1><<<dim3(D_/128, M_/128), 256, 0, stream>>>(xbf, wkT + lyr*DD, bk + lyr*D_, kb, D_, D_, 1.f);
    gemm_kernel<4><<<dim3(D_/128, M_/128), 256, 0, stream>>>(xbf, wvT + lyr*DD, bv + lyr*D_, vtG, D_, D_, 1.f);
    attn_kernel<<<dim3(B_*H_, (LP_+127)/128), 256, 0, stream>>>(qb, kb, vtG, obuf, lens);
    gemm_kernel<0><<<dim3(D_/128, M_/128), 256, 0, stream>>>(obuf, woT + lyr*DD, bo + lyr*D_, tmp, D_, D_, 1.f);
    ln_kernel<<<M_, 256, 0, stream>>>(xbf, tmp, ln1s + lyr*D_, ln1b + lyr*D_);
    gemm_kernel<2><<<dim3(F_/128, M_/128), 256, 0, stream>>>(xbf, fc1T + lyr*DF, fc1b + lyr*F_, hb, F_, D_, 1.f);
    gemm_kernel<0><<<dim3(D_/128, M_/128), 256, 0, stream>>>(hb, fc2T + lyr*DF, fc2b + lyr*D_, tmp, D_, F_, 1.f);
    ln_kernel<<<M_, 256, 0, stream>>>(xbf, tmp, ln2s + lyr*D_, ln2b + lyr*D_);
  }

  out_kernel<<<B_, 256, 0, stream>>>(xbf, outw, (float*)d_out);
}

// Round 3
// 1786.562 us; speedup vs baseline: 1.4340x; 1.2555x over previous
//
#include <hip/hip_runtime.h>
#include <hip/hip_bf16.h>
#include <stdint.h>

// ---------------- problem constants ----------------
#define D_   1024
#define H_   16
#define HD_  64
#define F_   4096
#define NL_  4
#define B_   16
#define TT_  128
#define TS_  512
#define LP_  704                  // max padded per-batch len (11*64); sum(padLb) <= B_*LP_? see plan
#define M_   (B_*LP_)

typedef __attribute__((ext_vector_type(8)))  __bf16 bf16x8;
typedef __attribute__((ext_vector_type(4)))  float  floatx4;

typedef __attribute__((address_space(3))) void lds_void_t;
typedef const __attribute__((address_space(1))) void g_void_t;

__device__ __forceinline__ void gl2lds16(const __bf16* g, const __bf16* l) {
  __builtin_amdgcn_global_load_lds((g_void_t*)g, (lds_void_t*)l, 16, 0, 0);
}

// ---------------- lens: tlen[b], Lb[b]=2+tlen+slen ----------------
__global__ void lens_kernel(const int* __restrict__ tmask, const int* __restrict__ smask,
                            int* __restrict__ lens) {
  __shared__ int red[256];
  int b = blockIdx.x, t = threadIdx.x;
  int tc = 0, sc = 0;
  if (t < TT_) tc = (tmask[b*TT_ + t] == 0) ? 1 : 0;
  for (int i = t; i < TS_; i += 256) sc += (smask[b*TS_ + i] == 0) ? 1 : 0;
  red[t] = tc + (sc << 16);
  __syncthreads();
  for (int s = 128; s > 0; s >>= 1) {
    if (t < s) red[t] += red[t + s];
    __syncthreads();
  }
  if (t == 0) {
    int tl = red[0] & 0xffff, sl = red[0] >> 16;
    if (tl < 0) tl = 0; if (tl > TT_) tl = TT_;
    if (sl < 0) sl = 0; if (sl > TS_) sl = TS_;
    int Lb = 2 + tl + sl;
    if (Lb > LP_) Lb = LP_;
    lens[2*b] = tl; lens[2*b+1] = Lb;
  }
}

// ---------------- plan: compacted per-batch offsets ----------------
// plan[0]=Mtiles(ceil(Mused/128)), plan[1]=Mused, plan[2+b]=off[b] (b=0..16)
__global__ void plan_kernel(const int* __restrict__ lens, int* __restrict__ plan) {
  if (threadIdx.x == 0 && blockIdx.x == 0) {
    int off = 0;
    for (int b = 0; b < B_; b++) {
      plan[2 + b] = off;
      int Lb = lens[2*b+1];
      int pad = ((Lb + 127) >> 7) << 7;
      if (pad > LP_) pad = LP_;               // Lb in (640,642] -> 704
      off += pad;
    }
    plan[2 + B_] = off;
    plan[1] = off;
    plan[0] = (off + 127) >> 7;
  }
}

// ---------------- fp32 [R,C] -> bf16 [C,R] transpose (batched over z) ----------------
__global__ void transpose_kernel(const float* __restrict__ in, __bf16* __restrict__ out,
                                 int R, int C) {
  __shared__ float tile[32][33];
  int x = threadIdx.x & 31, y0 = threadIdx.x >> 5;
  const float* inb = in + (size_t)blockIdx.z * R * C;
  __bf16* outb = out + (size_t)blockIdx.z * R * C;
  int r0 = blockIdx.y * 32, c0 = blockIdx.x * 32;
  #pragma unroll
  for (int i = 0; i < 4; i++) {
    int y = y0 + 8*i;
    tile[y][x] = inb[(size_t)(r0 + y)*C + c0 + x];
  }
  __syncthreads();
  #pragma unroll
  for (int i = 0; i < 4; i++) {
    int y = y0 + 8*i;
    outb[(size_t)(c0 + y)*R + r0 + x] = (__bf16)tile[x][y];
  }
}

// ---------------- build compacted x (bf16): CLS | text | SEP | speech | 0-pad ----------------
__global__ void build_x_kernel(const float* __restrict__ text, const float* __restrict__ speech,
                               const float* __restrict__ cls, const float* __restrict__ sep,
                               const int* __restrict__ lens, const int* __restrict__ plan,
                               __bf16* __restrict__ xbf) {
  int b = blockIdx.y, l = blockIdx.x;
  int off = plan[2+b], padLb = plan[3+b] - off;
  if (l >= padLb) return;
  int tl = lens[2*b], Lb = lens[2*b+1];
  const float* src = nullptr;          // nullptr => zero row
  if (l == 0)              src = cls;
  else if (l <= tl)        src = text   + ((size_t)(l-1)*B_ + b)*D_;
  else if (l == tl + 1)    src = sep;
  else if (l < Lb)         src = speech + ((size_t)(l-2-tl)*B_ + b)*D_;
  __bf16* dst = xbf + (size_t)(off + l) * D_;
  #pragma unroll
  for (int j = 0; j < 4; j++) {
    int i = threadIdx.x + j*256;
    float v = src ? src[i] : 0.f;
    dst[i] = (__bf16)v;
  }
}

// ---------------- GEMM: C[M,N] = A[M,K] @ BT[N,K]^T + bias ----------------
// MODE 0: fp32 out; 1: bf16 out; 2: bf16+relu; 3: bf16*scale; 4: bf16 transposed V store
template<int MODE>
__global__ __launch_bounds__(256, 2)
void gemm_kernel(const __bf16* __restrict__ A, const __bf16* __restrict__ BT,
                 const float* __restrict__ bias, void* __restrict__ Cv,
                 const int* __restrict__ plan, int Nn, int Kk, float scale) {
  if ((int)blockIdx.y >= plan[0]) return;       // compaction early-exit
  __shared__ __bf16 As[128*32];
  __shared__ __bf16 Bs[128*32];
  int tid = threadIdx.x;
  int w = tid >> 6, l = tid & 63;
  int wm = w >> 1, wn = w & 1;
  long tile_m = (long)blockIdx.y * 128;
  long tile_n = (long)blockIdx.x * 128;

  floatx4 acc[4][4] = {};

  const __bf16* ga = A  + (tile_m + w*32 + (l>>2)) * (long)Kk + (l&3)*8;
  const __bf16* gb = BT + (tile_n + w*32 + (l>>2)) * (long)Kk + (l&3)*8;
  const __bf16* lA = As + (w*32)*32;
  const __bf16* lB = Bs + (w*32)*32;

  int kcol = (l >> 4) * 8;
  const __bf16* afp = As + (wm*64 + (l&15))*32 + kcol;
  const __bf16* bfp = Bs + (wn*64 + (l&15))*32 + kcol;

  for (int k0 = 0; k0 < Kk; k0 += 32) {
    gl2lds16(ga,              lA);
    gl2lds16(ga + 16*(long)Kk, lA + 16*32);
    gl2lds16(gb,              lB);
    gl2lds16(gb + 16*(long)Kk, lB + 16*32);
    ga += 32; gb += 32;
    __syncthreads();
    bf16x8 af[4], bf[4];
    #pragma unroll
    for (int mi = 0; mi < 4; mi++) af[mi] = *(const bf16x8*)(afp + mi*16*32);
    #pragma unroll
    for (int ni = 0; ni < 4; ni++) bf[ni] = *(const bf16x8*)(bfp + ni*16*32);
    #pragma unroll
    for (int mi = 0; mi < 4; mi++)
      #pragma unroll
      for (int ni = 0; ni < 4; ni++)
        acc[mi][ni] = __builtin_amdgcn_mfma_f32_16x16x32_bf16(af[mi], bf[ni], acc[mi][ni], 0, 0, 0);
    __syncthreads();
  }

  int rbase = wm*64 + (l>>4)*4;
  int cbase = wn*64 + (l&15);
  #pragma unroll
  for (int mi = 0; mi < 4; mi++) {
    long row0 = tile_m + rbase + mi*16;
    long voff = 0;
    int bb = 0;
    if (MODE == 4) {                    // batch lookup (64-granular batches; 4-row quads don't straddle)
      #pragma unroll
      for (int t = 1; t < B_; t++) bb += (row0 >= plan[2+t]) ? 1 : 0;
      voff = plan[2+bb];
    }
    #pragma unroll
    for (int ni = 0; ni < 4; ni++) {
      long col = tile_n + cbase + ni*16;
      float bv = bias[col];
      #pragma unroll
      for (int r = 0; r < 4; r++) {
        long row = row0 + r;
        float v = acc[mi][ni][r] + bv;
        if (MODE == 3) v *= scale;
        if (MODE == 2) v = v > 0.f ? v : 0.f;
        if (MODE == 0)      ((float*)Cv)[row*Nn + col] = v;
        else if (MODE == 4) {
          long ll = row - voff;         // local seq pos
          if (ll < LP_)
            ((__bf16*)Cv)[(((long)bb*H_ + (col>>6))*HD_ + (col&63))*LP_ + ll] = (__bf16)v;
        }
        else                ((__bf16*)Cv)[row*Nn + col] = (__bf16)v;
      }
    }
  }
}

// ---------------- flash attention (compacted rows) ----------------
// q,k,o rows at off[b]+l, [.,H,HD] bf16; vt [B,H,HD,LP] bf16
__global__ __launch_bounds__(256, 2)
void attn_kernel(const __bf16* __restrict__ qb, const __bf16* __restrict__ kb,
                 const __bf16* __restrict__ vt, __bf16* __restrict__ ob,
                 const int* __restrict__ lens, const int* __restrict__ plan) {
  int col = blockIdx.x;               // b*H + h
  int b = col >> 4;
  int off = plan[2+b];
  int padLb = plan[3+b] - off;
  if ((int)blockIdx.y * 128 >= padLb) return;
  __shared__ __bf16 Ks[64*64];        // [key][hd-block ^ (key&7)]
  __shared__ __bf16 Vs[64*64];        // [hd][key-block ^ (hd&7)]
  __shared__ __bf16 Ps[4][32*72];     // per-wave P (2 m-frags), stride 72
  int tid = threadIdx.x, w = tid >> 6, l = tid & 63;
  int Lb = lens[2*b+1];
  int q0w = blockIdx.y*128 + w*32;
  const size_t bh  = (size_t)off*D_ + (size_t)(col & 15)*HD_;
  const size_t vtb = (size_t)col * HD_ * LP_;
  int nkt = (Lb + 63) >> 6;

  bf16x8 qf[2][2];
  #pragma unroll
  for (int mi = 0; mi < 2; mi++) {
    int qr = q0w + mi*16 + (l&15);
    if (qr > padLb-1) qr = padLb-1;   // 704-tail waves compute dummies
    const __bf16* qp = qb + bh + (size_t)qr*D_ + (l>>4)*8;
    qf[mi][0] = *(const bf16x8*)(qp);
    qf[mi][1] = *(const bf16x8*)(qp + 32);
  }
  bf16x8 ones;
  #pragma unroll
  for (int j = 0; j < 8; j++) ones[j] = (__bf16)1.0f;

  floatx4 oacc[2][4] = {};
  floatx4 lacc[2] = {};

  for (int kt = 0; kt < nkt; kt++) {
    int kbase = kt*64;
    { // stage K tile: 8 hd-blocks XOR-swizzled by key&7
      int krow = w*16 + (l>>3);
      int cb = (l&7) ^ (krow & 7);
      const __bf16* gk = kb + bh + (size_t)(kbase + krow)*D_ + cb*8;
      const __bf16* lk = Ks + (w*16)*64;
      gl2lds16(gk,                lk);
      gl2lds16(gk + 8*(size_t)D_, lk + 8*64);
    }
    { // stage V^T tile: 8 key-blocks XOR-swizzled by hd&7
      int vrow = w*8 + (l>>3);
      int sb = (l&7) ^ (l>>3);
      const __bf16* gv = vt + vtb + (size_t)vrow*LP_ + kbase + sb*8;
      const __bf16* lv = Vs + (w*8)*64;
      gl2lds16(gv,                  lv);
      gl2lds16(gv + 32*(size_t)LP_, lv + 32*64);
    }
    __syncthreads();

    floatx4 s4[2][4] = {};
    #pragma unroll
    for (int ks = 0; ks < 2; ks++) {
      #pragma unroll
      for (int ni = 0; ni < 4; ni++) {
        int n = ni*16 + (l&15);
        int blk = (ks*4 + (l>>4)) ^ (n & 7);
        bf16x8 kf = *(const bf16x8*)(Ks + n*64 + blk*8);
        s4[0][ni] = __builtin_amdgcn_mfma_f32_16x16x32_bf16(qf[0][ks], kf, s4[0][ni], 0, 0, 0);
        s4[1][ni] = __builtin_amdgcn_mfma_f32_16x16x32_bf16(qf[1][ks], kf, s4[1][ni], 0, 0, 0);
      }
    }
    #pragma unroll
    for (int mi = 0; mi < 2; mi++) {
      #pragma unroll
      for (int ni = 0; ni < 4; ni++) {
        int key = kbase + ni*16 + (l&15);
        bool valid = key < Lb;
        #pragma unroll
        for (int r = 0; r < 4; r++) {
          float sv = valid ? fminf(s4[mi][ni][r], 30.f) : -1e9f;
          float p = __expf(sv);
          Ps[w][(mi*16 + (l>>4)*4 + r)*72 + ni*16 + (l&15)] = (__bf16)p;
        }
      }
    }
    #pragma unroll
    for (int ks = 0; ks < 2; ks++) {
      bf16x8 pf0 = *(const bf16x8*)(&Ps[w][(l&15)*72 + ks*32 + (l>>4)*8]);
      bf16x8 pf1 = *(const bf16x8*)(&Ps[w][(16 + (l&15))*72 + ks*32 + (l>>4)*8]);
      lacc[0] = __builtin_amdgcn_mfma_f32_16x16x32_bf16(pf0, ones, lacc[0], 0, 0, 0);
      lacc[1] = __builtin_amdgcn_mfma_f32_16x16x32_bf16(pf1, ones, lacc[1], 0, 0, 0);
      #pragma unroll
      for (int ni = 0; ni < 4; ni++) {
        int n = ni*16 + (l&15);
        int blk = (ks*4 + (l>>4)) ^ (n & 7);
        bf16x8 vf = *(const bf16x8*)(Vs + n*64 + blk*8);
        oacc[0][ni] = __builtin_amdgcn_mfma_f32_16x16x32_bf16(pf0, vf, oacc[0][ni], 0, 0, 0);
        oacc[1][ni] = __builtin_amdgcn_mfma_f32_16x16x32_bf16(pf1, vf, oacc[1][ni], 0, 0, 0);
      }
    }
    __syncthreads();
  }

  #pragma unroll
  for (int mi = 0; mi < 2; mi++) {
    #pragma unroll
    for (int ni = 0; ni < 4; ni++) {
      #pragma unroll
      for (int r = 0; r < 4; r++) {
        int qrow = q0w + mi*16 + (l>>4)*4 + r;
        if (qrow < padLb) {
          float ov = oacc[mi][ni][r] / lacc[mi][r];
          ob[bh + (size_t)qrow*D_ + ni*16 + (l&15)] = (__bf16)ov;
        }
      }
    }
  }
}

// ---------------- post-norm LN: x = LN(x + t)*s + b (in-place on bf16 x) ----------------
__global__ void ln_kernel(__bf16* __restrict__ x, const float* __restrict__ t,
                          const float* __restrict__ sc, const float* __restrict__ bi,
                          const int* __restrict__ plan) {
  int row = blockIdx.x;
  if (row >= plan[1]) return;
  __shared__ float red[2][4];
  int tid = threadIdx.x;
  const float* tr = t + (size_t)row * D_;
  __bf16* xr = x + (size_t)row * D_;
  float v[4], s1 = 0.f, s2 = 0.f;
  #pragma unroll
  for (int j = 0; j < 4; j++) {
    int i = tid + j*256;
    float val = (float)xr[i] + tr[i];
    v[j] = val; s1 += val; s2 += val*val;
  }
  #pragma unroll
  for (int off = 1; off < 64; off <<= 1) {
    s1 += __shfl_xor(s1, off, 64);
    s2 += __shfl_xor(s2, off, 64);
  }
  int w = tid >> 6, l = tid & 63;
  if (l == 0) { red[0][w] = s1; red[1][w] = s2; }
  __syncthreads();
  s1 = red[0][0] + red[0][1] + red[0][2] + red[0][3];
  s2 = red[1][0] + red[1][1] + red[1][2] + red[1][3];
  float mean = s1 * (1.f/D_);
  float var  = s2 * (1.f/D_) - mean*mean;
  float rstd = rsqrtf(var + 1e-5f);
  #pragma unroll
  for (int j = 0; j < 4; j++) {
    int i = tid + j*256;
    xr[i] = (__bf16)((v[j] - mean)*rstd*sc[i] + bi[i]);
  }
}

// ---------------- final: out[b] = dot(x[off[b],:], out_w) ----------------
__global__ void out_kernel(const __bf16* __restrict__ x, const float* __restrict__ wv,
                           const int* __restrict__ plan, float* __restrict__ out) {
  __shared__ float red[4];
  int b = blockIdx.x, tid = threadIdx.x;
  const __bf16* xr = x + (size_t)plan[2+b] * D_;
  float s = 0.f;
  #pragma unroll
  for (int j = 0; j < 4; j++) {
    int i = tid + j*256;
    s += (float)xr[i] * wv[i];
  }
  #pragma unroll
  for (int off = 1; off < 64; off <<= 1) s += __shfl_xor(s, off, 64);
  int w = tid >> 6, l = tid & 63;
  if (l == 0) red[w] = s;
  __syncthreads();
  if (tid == 0) out[b] = red[0] + red[1] + red[2] + red[3];
}

// ---------------- launch ----------------
extern "C" void kernel_launch(void* const* d_in, const int* in_sizes, int n_in,
                              void* d_out, int out_size, void* d_ws, size_t ws_size,
                              hipStream_t stream) {
  (void)in_sizes; (void)n_in; (void)out_size; (void)ws_size;
  const float* text   = (const float*)d_in[0];
  const float* speech = (const float*)d_in[1];
  const int*   tmask  = (const int*)d_in[2];
  const int*   smask  = (const int*)d_in[3];
  const float* cls    = (const float*)d_in[4];
  const float* sep    = (const float*)d_in[5];
  const float* Wq     = (const float*)d_in[6];
  const float* bq     = (const float*)d_in[7];
  const float* Wk     = (const float*)d_in[8];
  const float* bk     = (const float*)d_in[9];
  const float* Wv     = (const float*)d_in[10];
  const float* bv     = (const float*)d_in[11];
  const float* Wo     = (const float*)d_in[12];
  const float* bo     = (const float*)d_in[13];
  const float* ln1s   = (const float*)d_in[14];
  const float* ln1b   = (const float*)d_in[15];
  const float* fc1w   = (const float*)d_in[16];
  const float* fc1b   = (const float*)d_in[17];
  const float* fc2w   = (const float*)d_in[18];
  const float* fc2b   = (const float*)d_in[19];
  const float* ln2s   = (const float*)d_in[20];
  const float* ln2b   = (const float*)d_in[21];
  const float* outw   = (const float*)d_in[22];

  const size_t MD = (size_t)M_ * D_;
  char* ws = (char*)d_ws;
  int*    lens = (int*)ws;                               // 32 ints
  int*    plan = (int*)(ws + 128);                       // 32 ints
  __bf16* xbf  = (__bf16*)(ws + 256);
  __bf16* act  = (__bf16*)(ws + 256 + MD*2);
  float*  tmp  = (float*) (ws + 256 + MD*2 + 4*MD*2);
  __bf16* wt   = (__bf16*)(ws + 256 + MD*2 + 4*MD*2 + MD*4);

  __bf16* qb   = act;
  __bf16* kb   = act + MD;
  __bf16* vtG  = act + 2*MD;                             // [B,H,HD,LP]
  __bf16* obuf = act + 3*MD;
  __bf16* hb   = act;                                    // [M, F] in FFN phase

  const size_t DD = (size_t)D_*D_;
  const size_t DF = (size_t)D_*F_;
  __bf16* wqT  = wt;
  __bf16* wkT  = wt + 4*DD;
  __bf16* wvT  = wt + 8*DD;
  __bf16* woT  = wt + 12*DD;
  __bf16* fc1T = wt + 16*DD;
  __bf16* fc2T = wt + 16*DD + 4*DF;

  lens_kernel<<<B_, 256, 0, stream>>>(tmask, smask, lens);
  plan_kernel<<<1, 64, 0, stream>>>(lens, plan);

  transpose_kernel<<<dim3(D_/32, D_/32, NL_), 256, 0, stream>>>(Wq, wqT, D_, D_);
  transpose_kernel<<<dim3(D_/32, D_/32, NL_), 256, 0, stream>>>(Wk, wkT, D_, D_);
  transpose_kernel<<<dim3(D_/32, D_/32, NL_), 256, 0, stream>>>(Wv, wvT, D_, D_);
  transpose_kernel<<<dim3(D_/32, D_/32, NL_), 256, 0, stream>>>(Wo, woT, D_, D_);
  transpose_kernel<<<dim3(F_/32, D_/32, NL_), 256, 0, stream>>>(fc1w, fc1T, D_, F_);
  transpose_kernel<<<dim3(D_/32, F_/32, NL_), 256, 0, stream>>>(fc2w, fc2T, F_, D_);

  build_x_kernel<<<dim3(LP_, B_), 256, 0, stream>>>(text, speech, cls, sep, lens, plan, xbf);

  for (int lyr = 0; lyr < NL_; lyr++) {
    gemm_kernel<3><<<dim3(D_/128, M_/128), 256, 0, stream>>>(xbf, wqT + lyr*DD, bq + lyr*D_, qb, plan, D_, D_, 0.125f);
    gemm_kernel<1><<<dim3(D_/128, M_/128), 256, 0, stream>>>(xbf, wkT + lyr*DD, bk + lyr*D_, kb, plan, D_, D_, 1.f);
    gemm_kernel<4><<<dim3(D_/128, M_/128), 256, 0, stream>>>(xbf, wvT + lyr*DD, bv + lyr*D_, vtG, plan, D_, D_, 1.f);
    attn_kernel<<<dim3(B_*H_, (LP_+127)/128), 256, 0, stream>>>(qb, kb, vtG, obuf, lens, plan);
    gemm_kernel<0><<<dim3(D_/128, M_/128), 256, 0, stream>>>(obuf, woT + lyr*DD, bo + lyr*D_, tmp, plan, D_, D_, 1.f);
    ln_kernel<<<M_, 256, 0, stream>>>(xbf, tmp, ln1s + lyr*D_, ln1b + lyr*D_, plan);
    gemm_kernel<2><<<dim3(F_/128, M_/128), 256, 0, stream>>>(xbf, fc1T + lyr*DF, fc1b + lyr*F_, hb, plan, F_, D_, 1.f);
    gemm_kernel<0><<<dim3(D_/128, M_/128), 256, 0, stream>>>(hb, fc2T + lyr*DF, fc2b + lyr*D_, tmp, plan, D_, F_, 1.f);
    ln_kernel<<<M_, 256, 0, stream>>>(xbf, tmp, ln2s + lyr*D_, ln2b + lyr*D_, plan);
  }

  out_kernel<<<B_, 256, 0, stream>>>(xbf, outw, plan, (float*)d_out);
}